// Round 2
// baseline (273.001 us; speedup 1.0000x reference)
//
#include <hip/hip_runtime.h>
#include <hip/hip_bf16.h>

constexpr int NN  = 50000;
constexpr int NN2 = 50048;
constexpr int NE  = 800000;
constexpr int SCAN_B = 1024;
constexpr int NB = (NN + SCAN_B - 1) / SCAN_B;    // 49 scan blocks
constexpr int GB = (NN + 63) / 64;                // 782 gemm blocks per chunk
constexpr int RANK_BLOCKS = (NE + 255) / 256;     // 3125 (place kernel)
constexpr int RANK4_BLOCKS = (NE / 4 + 255) / 256; // 782 (rank kernel, 4 edges/thread)

__device__ __forceinline__ float bfu_to_f(unsigned int u16) {
    return __uint_as_float(u16 << 16);
}
__device__ __forceinline__ unsigned short f_to_bfu(float f) {
    unsigned int u = __float_as_uint(f);
    return (unsigned short)((u + 0x7fffu + ((u >> 16) & 1u)) >> 16);
}

// real XCD id of the executing wave (0..7 on MI355X) — wave-uniform SGPR read
__device__ __forceinline__ int xcc_id() {
    int x;
    asm volatile("s_getreg_b32 %0, hwreg(HW_REG_XCC_ID, 0, 4)" : "=s"(x));
    return x & 7;
}

// ---------- layer-1 GEMM (2 chunks in one launch) ----------
// blocks [0, GB)   : chunk wc0=0
// blocks [GB, 2GB) : chunk wc0=64
__global__ __launch_bounds__(256) void gemm1_kernel(
        const float* __restrict__ X, const float* __restrict__ W,
        unsigned short* __restrict__ H) {
    constexpr int K = 128, N = 64, KT = 64, XS = K + 4;
    constexpr int CP = N / 4, RPT = 4;

    __shared__ float Xs[64 * XS];
    __shared__ float Ws[KT * N];

    const int bid = blockIdx.x;
    const int chunk = (bid < GB) ? 0 : 1;
    const int wc0 = chunk * 64;
    const int tid = threadIdx.x;
    const int rb  = (bid - chunk * GB) * 64;
    const int cp  = tid % CP;
    const int rg  = tid / CP;
    const int r0  = rg * RPT;

    {
        const float4* Xv  = reinterpret_cast<const float4*>(X + (size_t)rb * K);
        float4*       Xsv = reinterpret_cast<float4*>(Xs);
        constexpr int VPR = K / 4;
        for (int i = tid; i < 64 * VPR; i += 256) {
            int r = i / VPR, j = i - r * VPR;
            float4 v = make_float4(0.f, 0.f, 0.f, 0.f);
            if (rb + r < NN) v = Xv[i];
            Xsv[r * (XS / 4) + j] = v;
        }
    }

    float4 acc[RPT];
#pragma unroll
    for (int i = 0; i < RPT; i++) acc[i] = make_float4(0.f, 0.f, 0.f, 0.f);

    for (int kt = 0; kt < K; kt += KT) {
        {
            const float4* Wv  = reinterpret_cast<const float4*>(W);
            float4*       Wsv = reinterpret_cast<float4*>(Ws);
            constexpr int VPW = N / 4, VWR = 128 / 4;
            const int cv0 = wc0 / 4;
            for (int i = tid; i < KT * VPW; i += 256) {
                int k = i / VPW, j = i - k * VPW;
                Wsv[i] = Wv[(kt + k) * VWR + cv0 + j];
            }
        }
        __syncthreads();

        const float4* Xs4 = reinterpret_cast<const float4*>(Xs);
        const float4* Ws4 = reinterpret_cast<const float4*>(Ws);
#pragma unroll 4
        for (int k4 = 0; k4 < KT; k4 += 4) {
            float4 xq[RPT];
#pragma unroll
            for (int i = 0; i < RPT; i++)
                xq[i] = Xs4[(r0 + i) * (XS / 4) + (kt + k4) / 4];
            float4 wq[4];
#pragma unroll
            for (int j = 0; j < 4; j++) wq[j] = Ws4[(k4 + j) * CP + cp];
#pragma unroll
            for (int j = 0; j < 4; j++) {
#pragma unroll
                for (int i = 0; i < RPT; i++) {
                    float xx = reinterpret_cast<const float*>(&xq[i])[j];
                    acc[i].x += xx * wq[j].x;
                    acc[i].y += xx * wq[j].y;
                    acc[i].z += xx * wq[j].z;
                    acc[i].w += xx * wq[j].w;
                }
            }
        }
        __syncthreads();
    }

#pragma unroll
    for (int i = 0; i < RPT; i++) {
        int row = rb + r0 + i;
        if (row < NN) {
            ushort4 o;
            o.x = f_to_bfu(acc[i].x); o.y = f_to_bfu(acc[i].y);
            o.z = f_to_bfu(acc[i].z); o.w = f_to_bfu(acc[i].w);
            *reinterpret_cast<ushort4*>(H + (size_t)row * 128 + wc0 + 4 * cp) = o;
        }
    }
}

// ---------- rank: standalone, zero LDS, 4 edges/thread for deep MLP ----------
// pos[e] = rank within (replica, dst) bucket; replica = real XCD id, packed
// into bits [26:24] of pos so place_kernel can recover it.
__global__ __launch_bounds__(256, 8) void rank_kernel(
        const int* __restrict__ dst, int* __restrict__ cnt, int* __restrict__ pos) {
    int e0 = (blockIdx.x * 256 + threadIdx.x) * 4;
    if (e0 >= NE) return;   // NE % 4 == 0, so whole int4 is valid when e0 < NE
    const int rep = xcc_id();
    const int repb = rep << 24;
    int* c = cnt + rep * NN2;
    int4 d = *reinterpret_cast<const int4*>(dst + e0);
    int r0 = __hip_atomic_fetch_add(&c[d.x], 1, __ATOMIC_RELAXED, __HIP_MEMORY_SCOPE_WORKGROUP);
    int r1 = __hip_atomic_fetch_add(&c[d.y], 1, __ATOMIC_RELAXED, __HIP_MEMORY_SCOPE_WORKGROUP);
    int r2 = __hip_atomic_fetch_add(&c[d.z], 1, __ATOMIC_RELAXED, __HIP_MEMORY_SCOPE_WORKGROUP);
    int r3 = __hip_atomic_fetch_add(&c[d.w], 1, __ATOMIC_RELAXED, __HIP_MEMORY_SCOPE_WORKGROUP);
    int4 p = make_int4(r0 | repb, r1 | repb, r2 | repb, r3 | repb);
    *reinterpret_cast<int4*>(pos + e0) = p;
}

// ---------- reduce replicas: deg, dinv, per-replica offsets, scan partials ----------
__global__ __launch_bounds__(256) void reduce_kernel(const int* __restrict__ cnt,
                                                     int* __restrict__ deg,
                                                     int* __restrict__ roff,
                                                     float* __restrict__ dinv,
                                                     int* __restrict__ bsum, int n) {
    __shared__ int wred[4];
    const int tid = threadIdx.x, lane = tid & 63, wid = tid >> 6;
    int t0 = blockIdx.x * SCAN_B + tid * 4;
    int local = 0;
#pragma unroll
    for (int j = 0; j < 4; j++) {
        int t = t0 + j;
        if (t < n) {
            int acc = 0;
#pragma unroll
            for (int r = 0; r < 8; r++) {
                roff[r * NN2 + t] = acc;
                acc += cnt[r * NN2 + t];
            }
            deg[t] = acc;
            dinv[t] = rsqrtf((float)acc + 1.0f);
            local += acc;
        }
    }
#pragma unroll
    for (int off = 32; off >= 1; off >>= 1) local += __shfl_xor(local, off);
    if (lane == 0) wred[wid] = local;
    __syncthreads();
    if (tid == 0) bsum[blockIdx.x] = wred[0] + wred[1] + wred[2] + wred[3];
}

// ---------- one-wave exclusive scan of block sums ----------
__global__ __launch_bounds__(64) void scan_tops(const int* __restrict__ bsum,
                                                int* __restrict__ boff,
                                                int* __restrict__ total_out, int nb) {
    int lane = threadIdx.x;
    int v = (lane < nb) ? bsum[lane] : 0;
    int incl = v;
#pragma unroll
    for (int off = 1; off < 64; off <<= 1) {
        int t = __shfl_up(incl, off, 64);
        if (lane >= off) incl += t;
    }
    if (lane < nb) boff[lane] = incl - v;
    if (lane == 63) total_out[0] = incl;
}

// ---------- per-block scan + global offset -> rowptr ----------
__global__ __launch_bounds__(256) void scan_fill(const int* __restrict__ deg,
                                                 const int* __restrict__ boff,
                                                 int* __restrict__ rowptr, int n) {
    __shared__ int wsum[4];
    __shared__ int woff[4];
    const int tid = threadIdx.x, lane = tid & 63, wid = tid >> 6;
    int idx = blockIdx.x * SCAN_B + tid * 4;
    int v0 = (idx + 0 < n) ? deg[idx + 0] : 0;
    int v1 = (idx + 1 < n) ? deg[idx + 1] : 0;
    int v2 = (idx + 2 < n) ? deg[idx + 2] : 0;
    int v3 = (idx + 3 < n) ? deg[idx + 3] : 0;
    int local = v0 + v1 + v2 + v3;
    int incl = local;
#pragma unroll
    for (int off = 1; off < 64; off <<= 1) {
        int t = __shfl_up(incl, off, 64);
        if (lane >= off) incl += t;
    }
    if (lane == 63) wsum[wid] = incl;
    __syncthreads();
    if (tid == 0) {
        int acc = boff[blockIdx.x];
        for (int w = 0; w < 4; w++) { woff[w] = acc; acc += wsum[w]; }
    }
    __syncthreads();
    int p = woff[wid] + (incl - local);
    if (idx + 0 < n) rowptr[idx + 0] = p; p += v0;
    if (idx + 1 < n) rowptr[idx + 1] = p; p += v1;
    if (idx + 2 < n) rowptr[idx + 2] = p; p += v2;
    if (idx + 3 < n) rowptr[idx + 3] = p;
}

// ---------- place: srcs[rowptr[t] + roff[rep][t] + rank] = src[e] ----------
__global__ __launch_bounds__(256) void place_kernel(const int* __restrict__ src,
                                                    const int* __restrict__ dst,
                                                    const int* __restrict__ rowptr,
                                                    const int* __restrict__ roff,
                                                    const int* __restrict__ pos,
                                                    unsigned short* __restrict__ srcs,
                                                    int E) {
    int e = blockIdx.x * 256 + threadIdx.x;
    if (e >= E) return;
    int t = dst[e];
    int pr = pos[e];
    int rep = pr >> 24;                 // replica = XCD that ranked this edge
    srcs[rowptr[t] + roff[rep * NN2 + t] + (pr & 0xffffff)] = (unsigned short)src[e];
}

// ---------- GEMM (standalone, layer 2) ----------
template <int K, int N, int WN, int OS>
__global__ __launch_bounds__(256) void gemm_kernel(const float* __restrict__ X,
                                                   const float* __restrict__ W,
                                                   int wc0, int oc0,
                                                   unsigned short* __restrict__ H, int M) {
    constexpr int ROWS = 64, KT = 64, XS = K + 4;
    constexpr int CP = N / 4, NRG = 256 / CP, RPT = ROWS / NRG;

    __shared__ float Xs[ROWS * XS];
    __shared__ float Ws[KT * N];

    const int tid = threadIdx.x;
    const int rb  = blockIdx.x * ROWS;
    const int cp  = tid % CP;
    const int rg  = tid / CP;
    const int r0  = rg * RPT;

    {
        const float4* Xv  = reinterpret_cast<const float4*>(X + (size_t)rb * K);
        float4*       Xsv = reinterpret_cast<float4*>(Xs);
        constexpr int VPR = K / 4;
        for (int i = tid; i < ROWS * VPR; i += 256) {
            int r = i / VPR, j = i - r * VPR;
            float4 v = make_float4(0.f, 0.f, 0.f, 0.f);
            if (rb + r < M) v = Xv[i];
            Xsv[r * (XS / 4) + j] = v;
        }
    }

    float4 acc[RPT];
#pragma unroll
    for (int i = 0; i < RPT; i++) acc[i] = make_float4(0.f, 0.f, 0.f, 0.f);

    for (int kt = 0; kt < K; kt += KT) {
        {
            const float4* Wv  = reinterpret_cast<const float4*>(W);
            float4*       Wsv = reinterpret_cast<float4*>(Ws);
            constexpr int VPW = N / 4, VWR = WN / 4;
            const int cv0 = wc0 / 4;
            for (int i = tid; i < KT * VPW; i += 256) {
                int k = i / VPW, j = i - k * VPW;
                Wsv[i] = Wv[(kt + k) * VWR + cv0 + j];
            }
        }
        __syncthreads();

        const float4* Xs4 = reinterpret_cast<const float4*>(Xs);
        const float4* Ws4 = reinterpret_cast<const float4*>(Ws);
#pragma unroll 4
        for (int k4 = 0; k4 < KT; k4 += 4) {
            float4 xq[RPT];
#pragma unroll
            for (int i = 0; i < RPT; i++)
                xq[i] = Xs4[(r0 + i) * (XS / 4) + (kt + k4) / 4];
            float4 wq[4];
#pragma unroll
            for (int j = 0; j < 4; j++) wq[j] = Ws4[(k4 + j) * CP + cp];
#pragma unroll
            for (int j = 0; j < 4; j++) {
#pragma unroll
                for (int i = 0; i < RPT; i++) {
                    float xx = reinterpret_cast<const float*>(&xq[i])[j];
                    acc[i].x += xx * wq[j].x;
                    acc[i].y += xx * wq[j].y;
                    acc[i].z += xx * wq[j].z;
                    acc[i].w += xx * wq[j].w;
                }
            }
        }
        __syncthreads();
    }

#pragma unroll
    for (int i = 0; i < RPT; i++) {
        int row = rb + r0 + i;
        if (row < M) {
            ushort4 o;
            o.x = f_to_bfu(acc[i].x); o.y = f_to_bfu(acc[i].y);
            o.z = f_to_bfu(acc[i].z); o.w = f_to_bfu(acc[i].w);
            *reinterpret_cast<ushort4*>(H + (size_t)row * OS + oc0 + 4 * cp) = o;
        }
    }
}

// ---------- fused gather-aggregate + self-loop + bias (+relu): wave per node ----------
template <int NW, bool RELU>
__global__ __launch_bounds__(256) void gather_kernel(const int* __restrict__ rowptr,
                                                     const unsigned short* __restrict__ srcs,
                                                     const float* __restrict__ dinv,
                                                     const unsigned short* __restrict__ h,
                                                     const float* __restrict__ b,
                                                     float* __restrict__ out, int M) {
    constexpr int VEC = NW / 64;
    const int lane = threadIdx.x & 63;
    const int wid  = threadIdx.x >> 6;
    const int t    = blockIdx.x * 4 + wid;
    if (t >= M) return;

    float acc0 = 0.f, acc1 = 0.f;
    const int beg = rowptr[t], end = rowptr[t + 1];
    for (int eb = beg; eb < end; eb += 64) {
        const int rem = end - eb;
        int   sv = 0;
        float wv = 0.f;
        if (lane < rem) { sv = (int)srcs[eb + lane]; wv = dinv[sv]; }
        const int m = rem < 64 ? rem : 64;
        int j = 0;
        for (; j + 4 <= m; j += 4) {
            int s0 = __shfl(sv, j + 0), s1 = __shfl(sv, j + 1);
            int s2 = __shfl(sv, j + 2), s3 = __shfl(sv, j + 3);
            float w0 = __shfl(wv, j + 0), w1 = __shfl(wv, j + 1);
            float w2 = __shfl(wv, j + 2), w3 = __shfl(wv, j + 3);
            if constexpr (VEC == 2) {
                unsigned int h0 = *reinterpret_cast<const unsigned int*>(h + (size_t)s0 * NW + lane * 2);
                unsigned int h1 = *reinterpret_cast<const unsigned int*>(h + (size_t)s1 * NW + lane * 2);
                unsigned int h2 = *reinterpret_cast<const unsigned int*>(h + (size_t)s2 * NW + lane * 2);
                unsigned int h3 = *reinterpret_cast<const unsigned int*>(h + (size_t)s3 * NW + lane * 2);
                acc0 += w0 * bfu_to_f(h0 & 0xffffu); acc1 += w0 * bfu_to_f(h0 >> 16);
                acc0 += w1 * bfu_to_f(h1 & 0xffffu); acc1 += w1 * bfu_to_f(h1 >> 16);
                acc0 += w2 * bfu_to_f(h2 & 0xffffu); acc1 += w2 * bfu_to_f(h2 >> 16);
                acc0 += w3 * bfu_to_f(h3 & 0xffffu); acc1 += w3 * bfu_to_f(h3 >> 16);
            } else {
                unsigned short h0 = h[(size_t)s0 * NW + lane];
                unsigned short h1 = h[(size_t)s1 * NW + lane];
                unsigned short h2 = h[(size_t)s2 * NW + lane];
                unsigned short h3 = h[(size_t)s3 * NW + lane];
                acc0 += w0 * bfu_to_f(h0) + w1 * bfu_to_f(h1)
                      + w2 * bfu_to_f(h2) + w3 * bfu_to_f(h3);
            }
        }
        for (; j < m; j++) {
            int   s = __shfl(sv, j);
            float w = __shfl(wv, j);
            if constexpr (VEC == 2) {
                unsigned int hv = *reinterpret_cast<const unsigned int*>(
                    h + (size_t)s * NW + lane * 2);
                acc0 += w * bfu_to_f(hv & 0xffffu);
                acc1 += w * bfu_to_f(hv >> 16);
            } else {
                acc0 += w * bfu_to_f(h[(size_t)s * NW + lane]);
            }
        }
    }
    const float di = dinv[t];
    float* op = out + (size_t)t * NW + lane * VEC;
    if constexpr (VEC == 2) {
        unsigned int hv = *reinterpret_cast<const unsigned int*>(
            h + (size_t)t * NW + lane * 2);
        float2 bv = *reinterpret_cast<const float2*>(b + lane * 2);
        float v0 = acc0 * di + bfu_to_f(hv & 0xffffu) * di * di + bv.x;
        float v1 = acc1 * di + bfu_to_f(hv >> 16) * di * di + bv.y;
        if (RELU) { v0 = fmaxf(v0, 0.f); v1 = fmaxf(v1, 0.f); }
        *reinterpret_cast<float2*>(op) = make_float2(v0, v1);
    } else {
        float hs = bfu_to_f(h[(size_t)t * NW + lane]);
        float v0 = acc0 * di + hs * di * di + b[lane];
        if (RELU) v0 = fmaxf(v0, 0.f);
        op[0] = v0;
    }
}

extern "C" void kernel_launch(void* const* d_in, const int* in_sizes, int n_in,
                              void* d_out, int out_size, void* d_ws, size_t ws_size,
                              hipStream_t stream) {
    const float* x  = (const float*)d_in[0];
    const int*   ei = (const int*)d_in[1];
    const float* W1 = (const float*)d_in[2];
    const float* b1 = (const float*)d_in[3];
    const float* W2 = (const float*)d_in[4];
    const float* b2 = (const float*)d_in[5];

    float* out_h2 = (float*)d_out;                 // [NN x 64]
    float* out_h1 = out_h2 + (size_t)NN * 64;      // [NN x 128]

    const int* src = ei;
    const int* dst = ei + NE;

    // ws layout (4B words), ~21.5 MB of 256 MiB:
    int*   wsw    = (int*)d_ws;
    int*   cnt    = wsw;                        // 8*NN2 = 400384
    int*   deg    = wsw + 400384;               // 50048
    int*   rowptr = wsw + 450432;               // 50064
    float* dinv   = (float*)(wsw + 500496);     // 50048
    int*   bsum   = wsw + 550544;               // 64
    int*   boff   = wsw + 550608;               // 64
    int*   pos    = wsw + 550672;               // 800000
    int*   roff   = wsw + 1350672;              // 8*NN2 = 400384
    unsigned short* srcs = (unsigned short*)(wsw + 1751056);  // u16 [NE]
    unsigned short* T    = (unsigned short*)(wsw + 2151056);  // bf16 [NN x 128]

    // ----- rank (standalone, high occupancy) + layer-1 GEMM -----
    hipMemsetAsync(cnt, 0, 8 * NN2 * sizeof(int), stream);
    rank_kernel<<<RANK4_BLOCKS, 256, 0, stream>>>(dst, cnt, pos);
    gemm1_kernel<<<2 * GB, 256, 0, stream>>>(x, W1, T);

    // ----- CSR: reduce replicas -> scan -> place (atomic-free) -----
    reduce_kernel<<<NB, 256, 0, stream>>>(cnt, deg, roff, dinv, bsum, NN);
    scan_tops<<<1, 64, 0, stream>>>(bsum, boff, rowptr + NN, NB);
    scan_fill<<<NB, 256, 0, stream>>>(deg, boff, rowptr, NN);
    place_kernel<<<RANK_BLOCKS, 256, 0, stream>>>(src, dst, rowptr, roff, pos, srcs, NE);

    const int aB = (NN + 3) / 4;

    // ----- layer 1 gather -----
    gather_kernel<128, true><<<aB, 256, 0, stream>>>(rowptr, srcs, dinv, T,
                                                     b1, out_h1, NN);
    // ----- layer 2 -----
    gemm_kernel<128, 64, 64, 64><<<GB, 256, 0, stream>>>(out_h1, W2, 0, 0, T, NN);
    gather_kernel<64, false><<<aB, 256, 0, stream>>>(rowptr, srcs, dinv, T,
                                                     b2, out_h2, NN);
}

// Round 3
// 230.144 us; speedup vs baseline: 1.1862x; 1.1862x over previous
//
#include <hip/hip_runtime.h>
#include <hip/hip_bf16.h>

constexpr int NN  = 50000;
constexpr int NN2 = 50048;
constexpr int NE  = 800000;
constexpr int SCAN_B = 1024;
constexpr int NB = (NN + SCAN_B - 1) / SCAN_B;    // 49 scan blocks
constexpr int GB = (NN + 63) / 64;                // 782 gemm blocks (64 rows each)
constexpr int RANK_BLOCKS = (NE + 255) / 256;     // 3125 (place kernel)
constexpr int RANK4_BLOCKS = (NE / 4 + 255) / 256; // 782 (rank role, 4 edges/thread)

typedef short bf16x8 __attribute__((ext_vector_type(8)));
typedef float f32x4  __attribute__((ext_vector_type(4)));

__device__ __forceinline__ float bfu_to_f(unsigned int u16) {
    return __uint_as_float(u16 << 16);
}
__device__ __forceinline__ unsigned short f_to_bfu(float f) {
    unsigned int u = __float_as_uint(f);
    return (unsigned short)((u + 0x7fffu + ((u >> 16) & 1u)) >> 16);
}
__device__ __forceinline__ void split_bf16(float v, unsigned short& h, unsigned short& l) {
    h = f_to_bfu(v);
    l = f_to_bfu(v - bfu_to_f(h));
}

// real XCD id of the executing wave (0..7 on MI355X) — wave-uniform SGPR read
__device__ __forceinline__ int xcc_id() {
    int x;
    asm volatile("s_getreg_b32 %0, hwreg(HW_REG_XCC_ID, 0, 4)" : "=s"(x));
    return x & 7;
}

// ---------- W prep: transposed bf16 hi/lo tables Wt[n][k] ----------
__global__ __launch_bounds__(256) void wprep_kernel(
        const float* __restrict__ W1, const float* __restrict__ W2,
        unsigned short* __restrict__ wt1h, unsigned short* __restrict__ wt1l,
        unsigned short* __restrict__ wt2h, unsigned short* __restrict__ wt2l) {
    int i = blockIdx.x * 256 + threadIdx.x;
    if (i < 128 * 128) {
        int n = i >> 7, k = i & 127;
        unsigned short h, l;
        split_bf16(W1[k * 128 + n], h, l);
        wt1h[i] = h; wt1l[i] = l;
    }
    i -= 128 * 128;
    if (i >= 0 && i < 64 * 128) {
        int n = i >> 7, k = i & 127;
        unsigned short h, l;
        split_bf16(W2[k * 64 + n], h, l);
        wt2h[i] = h; wt2l[i] = l;
    }
}

// ---------- MFMA GEMM (bf16 split, fp32-accurate) + optional fused rank role ----------
// C[M x BN] = X[M x 128] @ W[128 x BN], H stored bf16 row-major stride BN.
// A-tile (64 x 128) staged once in LDS as bf16 hi/lo, XOR-swizzled; B from
// pre-transposed global bf16 tables Wt[n][128] (L2-resident).
// Fragment layout (16x16x32): A: lane l elem j = A[l&15][8*(l>>4)+j];
//                             B: lane l elem j = B[8*(l>>4)+j][l&15];
//                             D: lane l reg  j = D[4*(l>>4)+j][l&15]  (m89).
template <int BN, bool RANK>
__global__ __launch_bounds__(256) void mfma_gemm_kernel(
        const float* __restrict__ X,
        const unsigned short* __restrict__ Wth,
        const unsigned short* __restrict__ Wtl,
        unsigned short* __restrict__ H, int M,
        const int* __restrict__ dst, int* __restrict__ cnt, int* __restrict__ pos) {
    __shared__ unsigned short Ah[64 * 128];
    __shared__ unsigned short Al[64 * 128];

    const int bid = blockIdx.x;
    if constexpr (RANK) {
        if (bid >= GB) {
            // ---- rank role: pos[e] = rank within (XCD-replica, dst) bucket ----
            int e0 = ((bid - GB) * 256 + threadIdx.x) * 4;
            if (e0 < NE) {       // NE % 4 == 0
                const int rep = xcc_id();
                const int repb = rep << 24;
                int* c = cnt + rep * NN2;
                int4 d = *reinterpret_cast<const int4*>(dst + e0);
                int r0 = __hip_atomic_fetch_add(&c[d.x], 1, __ATOMIC_RELAXED, __HIP_MEMORY_SCOPE_WORKGROUP);
                int r1 = __hip_atomic_fetch_add(&c[d.y], 1, __ATOMIC_RELAXED, __HIP_MEMORY_SCOPE_WORKGROUP);
                int r2 = __hip_atomic_fetch_add(&c[d.z], 1, __ATOMIC_RELAXED, __HIP_MEMORY_SCOPE_WORKGROUP);
                int r3 = __hip_atomic_fetch_add(&c[d.w], 1, __ATOMIC_RELAXED, __HIP_MEMORY_SCOPE_WORKGROUP);
                *reinterpret_cast<int4*>(pos + e0) =
                    make_int4(r0 | repb, r1 | repb, r2 | repb, r3 | repb);
            }
            return;
        }
    }

    const int tid = threadIdx.x;
    const int rb  = bid * 64;

    // ---- stage X[rb..rb+64) -> Ah/Al (bf16 split, swizzled) ----
    {
        const float4* Xv = reinterpret_cast<const float4*>(X);
        char* AhB = reinterpret_cast<char*>(Ah);
        char* AlB = reinterpret_cast<char*>(Al);
        for (int i = tid; i < 64 * 32; i += 256) {
            int r = i >> 5, c4 = i & 31;               // col = 4*c4
            float4 v = make_float4(0.f, 0.f, 0.f, 0.f);
            if (rb + r < M) v = Xv[(size_t)(rb + r) * 32 + c4];
            ushort4 hi, lo;
            split_bf16(v.x, hi.x, lo.x);
            split_bf16(v.y, hi.y, lo.y);
            split_bf16(v.z, hi.z, lo.z);
            split_bf16(v.w, hi.w, lo.w);
            int b = (c4 * 8) ^ ((r & 7) << 4);         // in-row byte, 8B-aligned
            *reinterpret_cast<ushort4*>(AhB + r * 256 + b) = hi;
            *reinterpret_cast<ushort4*>(AlB + r * 256 + b) = lo;
        }
    }
    __syncthreads();

    const int lane = tid & 63;
    const int wv   = tid >> 6;
    constexpr int CT = BN / 64;            // col-tiles per wave (2 for 128, 1 for 64)
    const int wc0  = wv * (BN / 4);        // wave col base
    const int lr   = lane & 15;
    const int lg   = lane >> 4;

    f32x4 acc[4][CT];
#pragma unroll
    for (int rt = 0; rt < 4; rt++)
#pragma unroll
        for (int ct = 0; ct < CT; ct++)
            acc[rt][ct] = (f32x4){0.f, 0.f, 0.f, 0.f};

    const char* AhB = reinterpret_cast<const char*>(Ah);
    const char* AlB = reinterpret_cast<const char*>(Al);

#pragma unroll
    for (int k0 = 0; k0 < 128; k0 += 32) {
        bf16x8 ah[4], al[4];
#pragma unroll
        for (int rt = 0; rt < 4; rt++) {
            int row = rt * 16 + lr;
            int inb = (k0 * 2 + lg * 16) ^ ((row & 7) << 4);
            ah[rt] = *reinterpret_cast<const bf16x8*>(AhB + row * 256 + inb);
            al[rt] = *reinterpret_cast<const bf16x8*>(AlB + row * 256 + inb);
        }
#pragma unroll
        for (int ct = 0; ct < CT; ct++) {
            int n = wc0 + ct * 16 + lr;
            int off = n * 128 + k0 + lg * 8;
            bf16x8 bh = *reinterpret_cast<const bf16x8*>(Wth + off);
            bf16x8 bl = *reinterpret_cast<const bf16x8*>(Wtl + off);
#pragma unroll
            for (int rt = 0; rt < 4; rt++) {
                acc[rt][ct] = __builtin_amdgcn_mfma_f32_16x16x32_bf16(ah[rt], bh, acc[rt][ct], 0, 0, 0);
                acc[rt][ct] = __builtin_amdgcn_mfma_f32_16x16x32_bf16(ah[rt], bl, acc[rt][ct], 0, 0, 0);
                acc[rt][ct] = __builtin_amdgcn_mfma_f32_16x16x32_bf16(al[rt], bh, acc[rt][ct], 0, 0, 0);
            }
        }
    }

#pragma unroll
    for (int rt = 0; rt < 4; rt++)
#pragma unroll
        for (int ct = 0; ct < CT; ct++) {
            int col = wc0 + ct * 16 + lr;
#pragma unroll
            for (int j = 0; j < 4; j++) {
                int row = rb + rt * 16 + lg * 4 + j;
                if (row < M) H[(size_t)row * BN + col] = f_to_bfu(acc[rt][ct][j]);
            }
        }
}

// ---------- reduce replicas: deg, dinv, per-replica offsets, scan partials ----------
__global__ __launch_bounds__(256) void reduce_kernel(const int* __restrict__ cnt,
                                                     int* __restrict__ deg,
                                                     int* __restrict__ roff,
                                                     float* __restrict__ dinv,
                                                     int* __restrict__ bsum, int n) {
    __shared__ int wred[4];
    const int tid = threadIdx.x, lane = tid & 63, wid = tid >> 6;
    int t0 = blockIdx.x * SCAN_B + tid * 4;
    int local = 0;
#pragma unroll
    for (int j = 0; j < 4; j++) {
        int t = t0 + j;
        if (t < n) {
            int acc = 0;
#pragma unroll
            for (int r = 0; r < 8; r++) {
                roff[r * NN2 + t] = acc;
                acc += cnt[r * NN2 + t];
            }
            deg[t] = acc;
            dinv[t] = rsqrtf((float)acc + 1.0f);
            local += acc;
        }
    }
#pragma unroll
    for (int off = 32; off >= 1; off >>= 1) local += __shfl_xor(local, off);
    if (lane == 0) wred[wid] = local;
    __syncthreads();
    if (tid == 0) bsum[blockIdx.x] = wred[0] + wred[1] + wred[2] + wred[3];
}

// ---------- one-wave exclusive scan of block sums ----------
__global__ __launch_bounds__(64) void scan_tops(const int* __restrict__ bsum,
                                                int* __restrict__ boff,
                                                int* __restrict__ total_out, int nb) {
    int lane = threadIdx.x;
    int v = (lane < nb) ? bsum[lane] : 0;
    int incl = v;
#pragma unroll
    for (int off = 1; off < 64; off <<= 1) {
        int t = __shfl_up(incl, off, 64);
        if (lane >= off) incl += t;
    }
    if (lane < nb) boff[lane] = incl - v;
    if (lane == 63) total_out[0] = incl;
}

// ---------- per-block scan + global offset -> rowptr ----------
__global__ __launch_bounds__(256) void scan_fill(const int* __restrict__ deg,
                                                 const int* __restrict__ boff,
                                                 int* __restrict__ rowptr, int n) {
    __shared__ int wsum[4];
    __shared__ int woff[4];
    const int tid = threadIdx.x, lane = tid & 63, wid = tid >> 6;
    int idx = blockIdx.x * SCAN_B + tid * 4;
    int v0 = (idx + 0 < n) ? deg[idx + 0] : 0;
    int v1 = (idx + 1 < n) ? deg[idx + 1] : 0;
    int v2 = (idx + 2 < n) ? deg[idx + 2] : 0;
    int v3 = (idx + 3 < n) ? deg[idx + 3] : 0;
    int local = v0 + v1 + v2 + v3;
    int incl = local;
#pragma unroll
    for (int off = 1; off < 64; off <<= 1) {
        int t = __shfl_up(incl, off, 64);
        if (lane >= off) incl += t;
    }
    if (lane == 63) wsum[wid] = incl;
    __syncthreads();
    if (tid == 0) {
        int acc = boff[blockIdx.x];
        for (int w = 0; w < 4; w++) { woff[w] = acc; acc += wsum[w]; }
    }
    __syncthreads();
    int p = woff[wid] + (incl - local);
    if (idx + 0 < n) rowptr[idx + 0] = p; p += v0;
    if (idx + 1 < n) rowptr[idx + 1] = p; p += v1;
    if (idx + 2 < n) rowptr[idx + 2] = p; p += v2;
    if (idx + 3 < n) rowptr[idx + 3] = p;
}

// ---------- place: srcs[rowptr[t] + roff[rep][t] + rank] = src[e] ----------
__global__ __launch_bounds__(256) void place_kernel(const int* __restrict__ src,
                                                    const int* __restrict__ dst,
                                                    const int* __restrict__ rowptr,
                                                    const int* __restrict__ roff,
                                                    const int* __restrict__ pos,
                                                    unsigned short* __restrict__ srcs,
                                                    int E) {
    int e = blockIdx.x * 256 + threadIdx.x;
    if (e >= E) return;
    int t = dst[e];
    int pr = pos[e];
    int rep = pr >> 24;                 // replica = XCD that ranked this edge
    srcs[rowptr[t] + roff[rep * NN2 + t] + (pr & 0xffffff)] = (unsigned short)src[e];
}

// ---------- fused gather-aggregate + self-loop + bias (+relu): wave per node ----------
template <int NW, bool RELU>
__global__ __launch_bounds__(256) void gather_kernel(const int* __restrict__ rowptr,
                                                     const unsigned short* __restrict__ srcs,
                                                     const float* __restrict__ dinv,
                                                     const unsigned short* __restrict__ h,
                                                     const float* __restrict__ b,
                                                     float* __restrict__ out, int M) {
    constexpr int VEC = NW / 64;
    const int lane = threadIdx.x & 63;
    const int wid  = threadIdx.x >> 6;
    const int t    = blockIdx.x * 4 + wid;
    if (t >= M) return;

    float acc0 = 0.f, acc1 = 0.f;
    const int beg = rowptr[t], end = rowptr[t + 1];
    for (int eb = beg; eb < end; eb += 64) {
        const int rem = end - eb;
        int   sv = 0;
        float wv = 0.f;
        if (lane < rem) { sv = (int)srcs[eb + lane]; wv = dinv[sv]; }
        const int m = rem < 64 ? rem : 64;
        int j = 0;
        for (; j + 4 <= m; j += 4) {
            int s0 = __shfl(sv, j + 0), s1 = __shfl(sv, j + 1);
            int s2 = __shfl(sv, j + 2), s3 = __shfl(sv, j + 3);
            float w0 = __shfl(wv, j + 0), w1 = __shfl(wv, j + 1);
            float w2 = __shfl(wv, j + 2), w3 = __shfl(wv, j + 3);
            if constexpr (VEC == 2) {
                unsigned int h0 = *reinterpret_cast<const unsigned int*>(h + (size_t)s0 * NW + lane * 2);
                unsigned int h1 = *reinterpret_cast<const unsigned int*>(h + (size_t)s1 * NW + lane * 2);
                unsigned int h2 = *reinterpret_cast<const unsigned int*>(h + (size_t)s2 * NW + lane * 2);
                unsigned int h3 = *reinterpret_cast<const unsigned int*>(h + (size_t)s3 * NW + lane * 2);
                acc0 += w0 * bfu_to_f(h0 & 0xffffu); acc1 += w0 * bfu_to_f(h0 >> 16);
                acc0 += w1 * bfu_to_f(h1 & 0xffffu); acc1 += w1 * bfu_to_f(h1 >> 16);
                acc0 += w2 * bfu_to_f(h2 & 0xffffu); acc1 += w2 * bfu_to_f(h2 >> 16);
                acc0 += w3 * bfu_to_f(h3 & 0xffffu); acc1 += w3 * bfu_to_f(h3 >> 16);
            } else {
                unsigned short h0 = h[(size_t)s0 * NW + lane];
                unsigned short h1 = h[(size_t)s1 * NW + lane];
                unsigned short h2 = h[(size_t)s2 * NW + lane];
                unsigned short h3 = h[(size_t)s3 * NW + lane];
                acc0 += w0 * bfu_to_f(h0) + w1 * bfu_to_f(h1)
                      + w2 * bfu_to_f(h2) + w3 * bfu_to_f(h3);
            }
        }
        for (; j < m; j++) {
            int   s = __shfl(sv, j);
            float w = __shfl(wv, j);
            if constexpr (VEC == 2) {
                unsigned int hv = *reinterpret_cast<const unsigned int*>(
                    h + (size_t)s * NW + lane * 2);
                acc0 += w * bfu_to_f(hv & 0xffffu);
                acc1 += w * bfu_to_f(hv >> 16);
            } else {
                acc0 += w * bfu_to_f(h[(size_t)s * NW + lane]);
            }
        }
    }
    const float di = dinv[t];
    float* op = out + (size_t)t * NW + lane * VEC;
    if constexpr (VEC == 2) {
        unsigned int hv = *reinterpret_cast<const unsigned int*>(
            h + (size_t)t * NW + lane * 2);
        float2 bv = *reinterpret_cast<const float2*>(b + lane * 2);
        float v0 = acc0 * di + bfu_to_f(hv & 0xffffu) * di * di + bv.x;
        float v1 = acc1 * di + bfu_to_f(hv >> 16) * di * di + bv.y;
        if (RELU) { v0 = fmaxf(v0, 0.f); v1 = fmaxf(v1, 0.f); }
        *reinterpret_cast<float2*>(op) = make_float2(v0, v1);
    } else {
        float hs = bfu_to_f(h[(size_t)t * NW + lane]);
        float v0 = acc0 * di + hs * di * di + b[lane];
        if (RELU) v0 = fmaxf(v0, 0.f);
        op[0] = v0;
    }
}

extern "C" void kernel_launch(void* const* d_in, const int* in_sizes, int n_in,
                              void* d_out, int out_size, void* d_ws, size_t ws_size,
                              hipStream_t stream) {
    const float* x  = (const float*)d_in[0];
    const int*   ei = (const int*)d_in[1];
    const float* W1 = (const float*)d_in[2];
    const float* b1 = (const float*)d_in[3];
    const float* W2 = (const float*)d_in[4];
    const float* b2 = (const float*)d_in[5];

    float* out_h2 = (float*)d_out;                 // [NN x 64]
    float* out_h1 = out_h2 + (size_t)NN * 64;      // [NN x 128]

    const int* src = ei;
    const int* dst = ei + NE;

    // ws layout (4B words), ~21.5 MB of 256 MiB:
    int*   wsw    = (int*)d_ws;
    int*   cnt    = wsw;                        // 8*NN2 = 400384
    int*   deg    = wsw + 400384;               // 50048
    int*   rowptr = wsw + 450432;               // 50064
    float* dinv   = (float*)(wsw + 500496);     // 50048
    int*   bsum   = wsw + 550544;               // 64
    int*   boff   = wsw + 550608;               // 64
    int*   pos    = wsw + 550672;               // 800000
    int*   roff   = wsw + 1350672;              // 8*NN2 = 400384
    unsigned short* srcs = (unsigned short*)(wsw + 1751056);  // u16 [NE]
    unsigned short* T    = (unsigned short*)(wsw + 2151056);  // bf16 [NN x 128]
    unsigned short* wt1h = (unsigned short*)(wsw + 5351056);  // [128x128]
    unsigned short* wt1l = (unsigned short*)(wsw + 5359248);  // [128x128]
    unsigned short* wt2h = (unsigned short*)(wsw + 5367440);  // [64x128]
    unsigned short* wt2l = (unsigned short*)(wsw + 5371536);  // [64x128]

    // ----- W split/transpose prep (tiny) -----
    wprep_kernel<<<96, 256, 0, stream>>>(W1, W2, wt1h, wt1l, wt2h, wt2l);
    hipMemsetAsync(cnt, 0, 8 * NN2 * sizeof(int), stream);

    // ----- fused: layer-1 MFMA GEMM + rank histogram (overlapped roles) -----
    mfma_gemm_kernel<128, true><<<GB + RANK4_BLOCKS, 256, 0, stream>>>(
        x, wt1h, wt1l, T, NN, dst, cnt, pos);

    // ----- CSR: reduce replicas -> scan -> place (atomic-free) -----
    reduce_kernel<<<NB, 256, 0, stream>>>(cnt, deg, roff, dinv, bsum, NN);
    scan_tops<<<1, 64, 0, stream>>>(bsum, boff, rowptr + NN, NB);
    scan_fill<<<NB, 256, 0, stream>>>(deg, boff, rowptr, NN);
    place_kernel<<<RANK_BLOCKS, 256, 0, stream>>>(src, dst, rowptr, roff, pos, srcs, NE);

    const int aB = (NN + 3) / 4;

    // ----- layer 1 gather -----
    gather_kernel<128, true><<<aB, 256, 0, stream>>>(rowptr, srcs, dinv, T,
                                                     b1, out_h1, NN);
    // ----- layer 2 -----
    mfma_gemm_kernel<64, false><<<GB, 256, 0, stream>>>(
        out_h1, wt2h, wt2l, T, NN, nullptr, nullptr, nullptr);
    gather_kernel<64, false><<<aB, 256, 0, stream>>>(rowptr, srcs, dinv, T,
                                                     b2, out_h2, NN);
}

// Round 4
// 226.585 us; speedup vs baseline: 1.2049x; 1.0157x over previous
//
#include <hip/hip_runtime.h>
#include <hip/hip_bf16.h>

constexpr int NN  = 50000;
constexpr int NN2 = 50048;
constexpr int NE  = 800000;
constexpr int SCAN_B = 1024;
constexpr int NB = (NN + SCAN_B - 1) / SCAN_B;    // 49 scan blocks
constexpr int GB = (NN + 63) / 64;                // 782 gemm blocks (64 rows each)
constexpr int RANK_BLOCKS = (NE + 255) / 256;     // 3125 (place kernel)
constexpr int RANK4_BLOCKS = (NE / 4 + 255) / 256; // 782 (rank role, 4 edges/thread)

typedef short bf16x8 __attribute__((ext_vector_type(8)));
typedef float f32x4  __attribute__((ext_vector_type(4)));

__device__ __forceinline__ float bfu_to_f(unsigned int u16) {
    return __uint_as_float(u16 << 16);
}
__device__ __forceinline__ unsigned short f_to_bfu(float f) {
    unsigned int u = __float_as_uint(f);
    return (unsigned short)((u + 0x7fffu + ((u >> 16) & 1u)) >> 16);
}
__device__ __forceinline__ void split_bf16(float v, unsigned short& h, unsigned short& l) {
    h = f_to_bfu(v);
    l = f_to_bfu(v - bfu_to_f(h));
}

// real XCD id of the executing wave (0..7 on MI355X) — wave-uniform SGPR read
__device__ __forceinline__ int xcc_id() {
    int x;
    asm volatile("s_getreg_b32 %0, hwreg(HW_REG_XCC_ID, 0, 4)" : "=s"(x));
    return x & 7;
}

// ---------- W prep: transposed bf16 hi/lo tables Wt[n][k] ----------
__global__ __launch_bounds__(256) void wprep_kernel(
        const float* __restrict__ W1, const float* __restrict__ W2,
        unsigned short* __restrict__ wt1h, unsigned short* __restrict__ wt1l,
        unsigned short* __restrict__ wt2h, unsigned short* __restrict__ wt2l) {
    int i = blockIdx.x * 256 + threadIdx.x;
    if (i < 128 * 128) {
        int n = i >> 7, k = i & 127;
        unsigned short h, l;
        split_bf16(W1[k * 128 + n], h, l);
        wt1h[i] = h; wt1l[i] = l;
    }
    i -= 128 * 128;
    if (i >= 0 && i < 64 * 128) {
        int n = i >> 7, k = i & 127;
        unsigned short h, l;
        split_bf16(W2[k * 64 + n], h, l);
        wt2h[i] = h; wt2l[i] = l;
    }
}

// ---------- MFMA GEMM (bf16 split, fp32-accurate) + optional fused rank role ----------
// C[M x BN] = X[M x 128] @ W[128 x BN], H stored bf16 row-major stride BN.
// A-tile (64 x 128) staged once in LDS as bf16 hi/lo, XOR-swizzled; B from
// pre-transposed global bf16 tables Wt[n][128] (L2-resident).
// Fragment layout (16x16x32): A: lane l elem j = A[l&15][8*(l>>4)+j];
//                             B: lane l elem j = B[8*(l>>4)+j][l&15];
//                             D: lane l reg  j = D[4*(l>>4)+j][l&15]  (m89).
template <int BN, bool RANK>
__global__ __launch_bounds__(256) void mfma_gemm_kernel(
        const float* __restrict__ X,
        const unsigned short* __restrict__ Wth,
        const unsigned short* __restrict__ Wtl,
        unsigned short* __restrict__ H, int M,
        const int* __restrict__ dst, int* __restrict__ cnt, int* __restrict__ pos) {
    __shared__ unsigned short Ah[64 * 128];
    __shared__ unsigned short Al[64 * 128];

    const int bid = blockIdx.x;
    if constexpr (RANK) {
        if (bid >= GB) {
            // ---- rank role: pos[e] = rank within (XCD-replica, dst) bucket ----
            int e0 = ((bid - GB) * 256 + threadIdx.x) * 4;
            if (e0 < NE) {       // NE % 4 == 0
                const int rep = xcc_id();
                const int repb = rep << 24;
                int* c = cnt + rep * NN2;
                int4 d = *reinterpret_cast<const int4*>(dst + e0);
                int r0 = __hip_atomic_fetch_add(&c[d.x], 1, __ATOMIC_RELAXED, __HIP_MEMORY_SCOPE_WORKGROUP);
                int r1 = __hip_atomic_fetch_add(&c[d.y], 1, __ATOMIC_RELAXED, __HIP_MEMORY_SCOPE_WORKGROUP);
                int r2 = __hip_atomic_fetch_add(&c[d.z], 1, __ATOMIC_RELAXED, __HIP_MEMORY_SCOPE_WORKGROUP);
                int r3 = __hip_atomic_fetch_add(&c[d.w], 1, __ATOMIC_RELAXED, __HIP_MEMORY_SCOPE_WORKGROUP);
                *reinterpret_cast<int4*>(pos + e0) =
                    make_int4(r0 | repb, r1 | repb, r2 | repb, r3 | repb);
            }
            return;
        }
    }

    const int tid = threadIdx.x;
    const int rb  = bid * 64;

    // ---- stage X[rb..rb+64) -> Ah/Al (bf16 split, swizzled) ----
    {
        const float4* Xv = reinterpret_cast<const float4*>(X);
        char* AhB = reinterpret_cast<char*>(Ah);
        char* AlB = reinterpret_cast<char*>(Al);
        for (int i = tid; i < 64 * 32; i += 256) {
            int r = i >> 5, c4 = i & 31;               // col = 4*c4
            float4 v = make_float4(0.f, 0.f, 0.f, 0.f);
            if (rb + r < M) v = Xv[(size_t)(rb + r) * 32 + c4];
            ushort4 hi, lo;
            split_bf16(v.x, hi.x, lo.x);
            split_bf16(v.y, hi.y, lo.y);
            split_bf16(v.z, hi.z, lo.z);
            split_bf16(v.w, hi.w, lo.w);
            int b = (c4 * 8) ^ ((r & 7) << 4);         // in-row byte, 8B-aligned
            *reinterpret_cast<ushort4*>(AhB + r * 256 + b) = hi;
            *reinterpret_cast<ushort4*>(AlB + r * 256 + b) = lo;
        }
    }
    __syncthreads();

    const int lane = tid & 63;
    const int wv   = tid >> 6;
    constexpr int CT = BN / 64;            // col-tiles per wave (2 for 128, 1 for 64)
    const int wc0  = wv * (BN / 4);        // wave col base
    const int lr   = lane & 15;
    const int lg   = lane >> 4;

    f32x4 acc[4][CT];
#pragma unroll
    for (int rt = 0; rt < 4; rt++)
#pragma unroll
        for (int ct = 0; ct < CT; ct++)
            acc[rt][ct] = (f32x4){0.f, 0.f, 0.f, 0.f};

    const char* AhB = reinterpret_cast<const char*>(Ah);
    const char* AlB = reinterpret_cast<const char*>(Al);

#pragma unroll
    for (int k0 = 0; k0 < 128; k0 += 32) {
        bf16x8 ah[4], al[4];
#pragma unroll
        for (int rt = 0; rt < 4; rt++) {
            int row = rt * 16 + lr;
            int inb = (k0 * 2 + lg * 16) ^ ((row & 7) << 4);
            ah[rt] = *reinterpret_cast<const bf16x8*>(AhB + row * 256 + inb);
            al[rt] = *reinterpret_cast<const bf16x8*>(AlB + row * 256 + inb);
        }
#pragma unroll
        for (int ct = 0; ct < CT; ct++) {
            int n = wc0 + ct * 16 + lr;
            int off = n * 128 + k0 + lg * 8;
            bf16x8 bh = *reinterpret_cast<const bf16x8*>(Wth + off);
            bf16x8 bl = *reinterpret_cast<const bf16x8*>(Wtl + off);
#pragma unroll
            for (int rt = 0; rt < 4; rt++) {
                acc[rt][ct] = __builtin_amdgcn_mfma_f32_16x16x32_bf16(ah[rt], bh, acc[rt][ct], 0, 0, 0);
                acc[rt][ct] = __builtin_amdgcn_mfma_f32_16x16x32_bf16(ah[rt], bl, acc[rt][ct], 0, 0, 0);
                acc[rt][ct] = __builtin_amdgcn_mfma_f32_16x16x32_bf16(al[rt], bh, acc[rt][ct], 0, 0, 0);
            }
        }
    }

#pragma unroll
    for (int rt = 0; rt < 4; rt++)
#pragma unroll
        for (int ct = 0; ct < CT; ct++) {
            int col = wc0 + ct * 16 + lr;
#pragma unroll
            for (int j = 0; j < 4; j++) {
                int row = rb + rt * 16 + lg * 4 + j;
                if (row < M) H[(size_t)row * BN + col] = f_to_bfu(acc[rt][ct][j]);
            }
        }
}

// ---------- reduce replicas: deg, dinv, per-replica offsets, scan partials ----------
__global__ __launch_bounds__(256) void reduce_kernel(const int* __restrict__ cnt,
                                                     int* __restrict__ deg,
                                                     int* __restrict__ roff,
                                                     float* __restrict__ dinv,
                                                     int* __restrict__ bsum, int n) {
    __shared__ int wred[4];
    const int tid = threadIdx.x, lane = tid & 63, wid = tid >> 6;
    int t0 = blockIdx.x * SCAN_B + tid * 4;
    int local = 0;
#pragma unroll
    for (int j = 0; j < 4; j++) {
        int t = t0 + j;
        if (t < n) {
            int acc = 0;
#pragma unroll
            for (int r = 0; r < 8; r++) {
                roff[r * NN2 + t] = acc;
                acc += cnt[r * NN2 + t];
            }
            deg[t] = acc;
            dinv[t] = rsqrtf((float)acc + 1.0f);
            local += acc;
        }
    }
#pragma unroll
    for (int off = 32; off >= 1; off >>= 1) local += __shfl_xor(local, off);
    if (lane == 0) wred[wid] = local;
    __syncthreads();
    if (tid == 0) bsum[blockIdx.x] = wred[0] + wred[1] + wred[2] + wred[3];
}

// ---------- one-wave exclusive scan of block sums ----------
__global__ __launch_bounds__(64) void scan_tops(const int* __restrict__ bsum,
                                                int* __restrict__ boff,
                                                int* __restrict__ total_out, int nb) {
    int lane = threadIdx.x;
    int v = (lane < nb) ? bsum[lane] : 0;
    int incl = v;
#pragma unroll
    for (int off = 1; off < 64; off <<= 1) {
        int t = __shfl_up(incl, off, 64);
        if (lane >= off) incl += t;
    }
    if (lane < nb) boff[lane] = incl - v;
    if (lane == 63) total_out[0] = incl;
}

// ---------- per-block scan + global offset -> rowptr ----------
__global__ __launch_bounds__(256) void scan_fill(const int* __restrict__ deg,
                                                 const int* __restrict__ boff,
                                                 int* __restrict__ rowptr, int n) {
    __shared__ int wsum[4];
    __shared__ int woff[4];
    const int tid = threadIdx.x, lane = tid & 63, wid = tid >> 6;
    int idx = blockIdx.x * SCAN_B + tid * 4;
    int v0 = (idx + 0 < n) ? deg[idx + 0] : 0;
    int v1 = (idx + 1 < n) ? deg[idx + 1] : 0;
    int v2 = (idx + 2 < n) ? deg[idx + 2] : 0;
    int v3 = (idx + 3 < n) ? deg[idx + 3] : 0;
    int local = v0 + v1 + v2 + v3;
    int incl = local;
#pragma unroll
    for (int off = 1; off < 64; off <<= 1) {
        int t = __shfl_up(incl, off, 64);
        if (lane >= off) incl += t;
    }
    if (lane == 63) wsum[wid] = incl;
    __syncthreads();
    if (tid == 0) {
        int acc = boff[blockIdx.x];
        for (int w = 0; w < 4; w++) { woff[w] = acc; acc += wsum[w]; }
    }
    __syncthreads();
    int p = woff[wid] + (incl - local);
    if (idx + 0 < n) rowptr[idx + 0] = p; p += v0;
    if (idx + 1 < n) rowptr[idx + 1] = p; p += v1;
    if (idx + 2 < n) rowptr[idx + 2] = p; p += v2;
    if (idx + 3 < n) rowptr[idx + 3] = p;
}

// ---------- place: srcs[rowptr[t] + roff[rep][t] + rank] = src[e] ----------
__global__ __launch_bounds__(256) void place_kernel(const int* __restrict__ src,
                                                    const int* __restrict__ dst,
                                                    const int* __restrict__ rowptr,
                                                    const int* __restrict__ roff,
                                                    const int* __restrict__ pos,
                                                    unsigned short* __restrict__ srcs,
                                                    int E) {
    int e = blockIdx.x * 256 + threadIdx.x;
    if (e >= E) return;
    int t = dst[e];
    int pr = pos[e];
    int rep = pr >> 24;                 // replica = XCD that ranked this edge
    srcs[rowptr[t] + roff[rep * NN2 + t] + (pr & 0xffffff)] = (unsigned short)src[e];
}

// ---------- fused gather-aggregate + self-loop + bias (+relu) ----------
// Wave per node; LPR = NW/8 lanes cooperate on one source row (16 B bf16x8
// per lane), so one wave processes 64/LPR rows per load issue. Inactive
// lanes carry sv=0/wv=0 so tail rows need no guard (w=0 kills the term,
// row 0 is always valid memory). Partial sums per lane-group are combined
// once per node with a shfl_xor butterfly.
template <int NW, bool RELU>
__global__ __launch_bounds__(256) void gather_kernel(const int* __restrict__ rowptr,
                                                     const unsigned short* __restrict__ srcs,
                                                     const float* __restrict__ dinv,
                                                     const unsigned short* __restrict__ h,
                                                     const float* __restrict__ b,
                                                     float* __restrict__ out, int M) {
    constexpr int LPR = NW / 8;        // lanes per source row (16 / 8)
    constexpr int RPW = 64 / LPR;      // rows per wave-step   (4  / 8)
    const int lane = threadIdx.x & 63;
    const int wid  = threadIdx.x >> 6;
    const int t    = blockIdx.x * 4 + wid;
    if (t >= M) return;
    const int sl = lane % LPR;         // column slice: cols [sl*8, sl*8+8)
    const int sr = lane / LPR;         // sub-row within wave-step

    float acc[8];
#pragma unroll
    for (int c = 0; c < 8; c++) acc[c] = 0.f;

    const int beg = rowptr[t], end = rowptr[t + 1];
    for (int eb = beg; eb < end; eb += 64) {
        const int rem = end - eb;
        int   sv = 0;
        float wv = 0.f;
        if (lane < rem) { sv = (int)srcs[eb + lane]; wv = dinv[sv]; }
        const int m = rem < 64 ? rem : 64;
        for (int j = 0; j < m; j += RPW) {
            int   s = __shfl(sv, j + sr);
            float w = __shfl(wv, j + sr);
            bf16x8 hv = *reinterpret_cast<const bf16x8*>(h + (size_t)s * NW + sl * 8);
#pragma unroll
            for (int c = 0; c < 8; c++)
                acc[c] += w * bfu_to_f((unsigned short)hv[c]);
        }
    }

    // combine the 64/LPR sub-row partials (butterfly -> all lanes hold total)
#pragma unroll
    for (int off = LPR; off < 64; off <<= 1)
#pragma unroll
        for (int c = 0; c < 8; c++) acc[c] += __shfl_xor(acc[c], off);

    if (sr == 0) {
        const float di = dinv[t];
        bf16x8 own = *reinterpret_cast<const bf16x8*>(h + (size_t)t * NW + sl * 8);
        float4 b0 = *reinterpret_cast<const float4*>(b + sl * 8);
        float4 b1 = *reinterpret_cast<const float4*>(b + sl * 8 + 4);
        float v[8];
#pragma unroll
        for (int c = 0; c < 8; c++) {
            float bc = (c < 4) ? (&b0.x)[c] : (&b1.x)[c - 4];
            v[c] = acc[c] * di + bfu_to_f((unsigned short)own[c]) * di * di + bc;
            if (RELU) v[c] = fmaxf(v[c], 0.f);
        }
        float* op = out + (size_t)t * NW + sl * 8;
        *reinterpret_cast<float4*>(op)     = make_float4(v[0], v[1], v[2], v[3]);
        *reinterpret_cast<float4*>(op + 4) = make_float4(v[4], v[5], v[6], v[7]);
    }
}

extern "C" void kernel_launch(void* const* d_in, const int* in_sizes, int n_in,
                              void* d_out, int out_size, void* d_ws, size_t ws_size,
                              hipStream_t stream) {
    const float* x  = (const float*)d_in[0];
    const int*   ei = (const int*)d_in[1];
    const float* W1 = (const float*)d_in[2];
    const float* b1 = (const float*)d_in[3];
    const float* W2 = (const float*)d_in[4];
    const float* b2 = (const float*)d_in[5];

    float* out_h2 = (float*)d_out;                 // [NN x 64]
    float* out_h1 = out_h2 + (size_t)NN * 64;      // [NN x 128]

    const int* src = ei;
    const int* dst = ei + NE;

    // ws layout (4B words), ~21.5 MB of 256 MiB:
    int*   wsw    = (int*)d_ws;
    int*   cnt    = wsw;                        // 8*NN2 = 400384
    int*   deg    = wsw + 400384;               // 50048
    int*   rowptr = wsw + 450432;               // 50064
    float* dinv   = (float*)(wsw + 500496);     // 50048
    int*   bsum   = wsw + 550544;               // 64
    int*   boff   = wsw + 550608;               // 64
    int*   pos    = wsw + 550672;               // 800000
    int*   roff   = wsw + 1350672;              // 8*NN2 = 400384
    unsigned short* srcs = (unsigned short*)(wsw + 1751056);  // u16 [NE]
    unsigned short* T    = (unsigned short*)(wsw + 2151056);  // bf16 [NN x 128]
    unsigned short* wt1h = (unsigned short*)(wsw + 5351056);  // [128x128]
    unsigned short* wt1l = (unsigned short*)(wsw + 5359248);  // [128x128]
    unsigned short* wt2h = (unsigned short*)(wsw + 5367440);  // [64x128]
    unsigned short* wt2l = (unsigned short*)(wsw + 5371536);  // [64x128]

    // ----- W split/transpose prep (tiny) -----
    wprep_kernel<<<96, 256, 0, stream>>>(W1, W2, wt1h, wt1l, wt2h, wt2l);
    hipMemsetAsync(cnt, 0, 8 * NN2 * sizeof(int), stream);

    // ----- fused: layer-1 MFMA GEMM + rank histogram (overlapped roles) -----
    mfma_gemm_kernel<128, true><<<GB + RANK4_BLOCKS, 256, 0, stream>>>(
        x, wt1h, wt1l, T, NN, dst, cnt, pos);

    // ----- CSR: reduce replicas -> scan -> place (atomic-free) -----
    reduce_kernel<<<NB, 256, 0, stream>>>(cnt, deg, roff, dinv, bsum, NN);
    scan_tops<<<1, 64, 0, stream>>>(bsum, boff, rowptr + NN, NB);
    scan_fill<<<NB, 256, 0, stream>>>(deg, boff, rowptr, NN);
    place_kernel<<<RANK_BLOCKS, 256, 0, stream>>>(src, dst, rowptr, roff, pos, srcs, NE);

    const int aB = (NN + 3) / 4;

    // ----- layer 1 gather -----
    gather_kernel<128, true><<<aB, 256, 0, stream>>>(rowptr, srcs, dinv, T,
                                                     b1, out_h1, NN);
    // ----- layer 2 -----
    mfma_gemm_kernel<64, false><<<GB, 256, 0, stream>>>(
        out_h1, wt2h, wt2l, T, NN, nullptr, nullptr, nullptr);
    gather_kernel<64, false><<<aB, 256, 0, stream>>>(rowptr, srcs, dinv, T,
                                                     b2, out_h2, NN);
}